// Round 13
// baseline (1726.733 us; speedup 1.0000x reference)
//
#include <hip/hip_runtime.h>
#include <hip/hip_bf16.h>
#include <stdint.h>

// Problem constants
#define VV   30000
#define EE   1024
#define SHH  2048
#define HH   1024
#define H2   2048
#define G3   6144      // 3*H2
#define BB   64
#define TT   50
#define PADT 10003
#define MM   3200      // T*B
#define NPAD2 30208    // V padded to 256
#define RBLK 64        // persistent recurrence blocks
#define PNB2 (NPAD2 / 128)  // 236 LSE partials per row (128-col groups)

typedef __bf16 bf16;
typedef bf16  bf16x8 __attribute__((ext_vector_type(8)));
typedef bf16  bf16x4v __attribute__((ext_vector_type(4)));
typedef float f32x4 __attribute__((ext_vector_type(4)));

__device__ __forceinline__ void async16(void* lds_base, const void* gsrc) {
    __builtin_amdgcn_global_load_lds(
        (const __attribute__((address_space(1))) void*)gsrc,
        (__attribute__((address_space(3))) void*)lds_base, 16, 0, 0);
}

// bijective XCD-aware swizzle (m204)
__device__ __forceinline__ int xcd_swizzle(int lin, int nwg) {
    int q = nwg >> 3, r = nwg & 7;
    int x = lin & 7, o = lin >> 3;
    return (x < r ? x * (q + 1) : r * (q + 1) + (x - r) * q) + o;
}

__device__ __forceinline__ float sigmoidf_(float x) {
    return 1.f / (1.f + __expf(-x));
}

// ---------------- conversion kernels ----------------
__global__ __launch_bounds__(256) void k_conv(bf16* dst, const float* src, int n) {
    int i = (blockIdx.x * 256 + threadIdx.x) * 4;
    if (i + 3 >= n) return;
    float4 v = *(const float4*)&src[i];
    bf16x4v o; o[0] = (bf16)v.x; o[1] = (bf16)v.y; o[2] = (bf16)v.z; o[3] = (bf16)v.w;
    *(bf16x4v*)&dst[i] = o;
}

__global__ __launch_bounds__(256) void k_conv_outw(bf16* dst, const float* src) {
    int row = blockIdx.x;            // 0..30207
    int c = threadIdx.x * 4;
    bf16x4v o;
    if (row < VV) {
        float4 v = *(const float4*)&src[(size_t)row * EE + c];
        o[0] = (bf16)v.x; o[1] = (bf16)v.y; o[2] = (bf16)v.z; o[3] = (bf16)v.w;
    } else {
        o[0] = (bf16)0.f; o[1] = (bf16)0.f; o[2] = (bf16)0.f; o[3] = (bf16)0.f;
    }
    *(bf16x4v*)&dst[(size_t)row * EE + c] = o;
}

// Whh hi-col rows reordered for k_hi: dst row d = cblk*192 + g*64 + s
__global__ __launch_bounds__(256) void k_conv_whhhi(bf16* dst, const float* whh) {
    int d = blockIdx.x;              // 0..3071
    int cblk = d / 192, rem = d % 192, g = rem / 64, s = rem % 64;
    const float* srow = whh + (size_t)(g * H2 + 1024 + cblk * 64 + s) * H2;
    int c = threadIdx.x * 4;
    float4 v = *(const float4*)&srow[c];
    bf16x4v o; o[0] = (bf16)v.x; o[1] = (bf16)v.y; o[2] = (bf16)v.z; o[3] = (bf16)v.w;
    *(bf16x4v*)&dst[(size_t)d * HH + c] = o;
}

__global__ __launch_bounds__(256) void k_embed(const int* x, const float* embW, bf16* out) {
    int i = blockIdx.x;              // row = t*64+b
    int t = i >> 6, b = i & 63;
    int tok = x[b * TT + t];
    int e = threadIdx.x * 4;
    bf16x4v o;
    if (tok == PADT) {
        o[0] = (bf16)0.f; o[1] = (bf16)0.f; o[2] = (bf16)0.f; o[3] = (bf16)0.f;
    } else {
        float4 v = *(const float4*)&embW[(size_t)tok * EE + e];
        o[0] = (bf16)v.x; o[1] = (bf16)v.y; o[2] = (bf16)v.z; o[3] = (bf16)v.w;
    }
    *(bf16x4v*)&out[(size_t)i * EE + e] = o;
}

// ---------------- small fp32 GEMM (M=64): ses and ghs ----------------
template<int KIND>
__global__ __launch_bounds__(256)
void sgemm64(const float* __restrict__ A, const float* __restrict__ Bm,
             const float* __restrict__ bias, float* __restrict__ Of,
             bf16* __restrict__ Ob, bf16* __restrict__ Ob2,
             int N, int K, int lda, int ldb, int koff, int ldo, int ldo2) {
    int n0 = blockIdx.x * 64;
    int tid = threadIdx.x;
    int tr = tid >> 4, tc = tid & 15;
    __shared__ float As[64][33];
    __shared__ float Bs[64][33];
    float acc[4][4] = {};
    for (int k0 = 0; k0 < K; k0 += 32) {
        #pragma unroll
        for (int q = 0; q < 8; ++q) {
            int p = q * 256 + tid; int r = p >> 5, kk = p & 31;
            As[r][kk] = A[(size_t)r * lda + k0 + kk];
            Bs[r][kk] = Bm[(size_t)(n0 + r) * ldb + koff + k0 + kk];
        }
        __syncthreads();
        #pragma unroll
        for (int kk = 0; kk < 32; ++kk) {
            float a4[4], b4[4];
            #pragma unroll
            for (int i = 0; i < 4; i++) a4[i] = As[tr * 4 + i][kk];
            #pragma unroll
            for (int j = 0; j < 4; j++) b4[j] = Bs[tc * 4 + j][kk];
            #pragma unroll
            for (int i = 0; i < 4; i++)
                #pragma unroll
                for (int j = 0; j < 4; j++) acc[i][j] += a4[i] * b4[j];
        }
        __syncthreads();
    }
    #pragma unroll
    for (int i = 0; i < 4; i++)
        #pragma unroll
        for (int j = 0; j < 4; j++) {
            int row = tr * 4 + i, col = n0 + tc * 4 + j;
            float v = acc[i][j] + bias[col];
            if (KIND == 0) {
                v = tanhf(v);
                Of[(size_t)row * N + col] = v;
                Ob[(size_t)row * ldo + col] = (bf16)v;
                Ob2[(size_t)row * ldo2 + col] = (bf16)v;
            } else {
                Of[(size_t)row * N + col] = v;
            }
        }
}

// ---------------- big bf16 MFMA GEMM, 128xTN tile, 2-phase pipelined ----------------
// TN=128: 4 waves 2x2, wave tile 64x64.  TN=256: 4 waves 2x2, wave tile 64x128.
// KIND 0: bf16 out + bias (gi) ; KIND 1: bf16 out + bias + bf16 addend (hid_o)
// KIND 2: f32 NT-store out, row-transposed, col guard, fused partial-LSE (logits)
template<int KIND, int TN>
__global__ __launch_bounds__(256)
void gemm128(const bf16* __restrict__ A, const bf16* __restrict__ Bm,
             void* __restrict__ Cout, const float* __restrict__ bias,
             const bf16* __restrict__ addend, float* __restrict__ pm,
             float* __restrict__ ps, int N, int K, int lda, int ldb, int Nreal) {
    constexpr int NI = TN / 32;          // 4 or 8 fragments per wave in N
    constexpr int BQ = TN / 64;          // B stage chunks per thread: 2 or 4
    int nwg = gridDim.x * gridDim.y;
    int lin = blockIdx.y * gridDim.x + blockIdx.x;
    int wg = xcd_swizzle(lin, nwg);
    int bx = wg % gridDim.x, by = wg / gridDim.x;
    const int n0 = bx * TN;
    const int m0 = by * 128;
    const int tid = threadIdx.x;
    const int w = tid >> 6, l = tid & 63;
    const int wr = w >> 1, wc = w & 1;
    __shared__ bf16 As[2][128 * 32];
    __shared__ bf16 Bs[2][TN * 32];
    f32x4 acc[4][NI] = {};
    const int lrow = l >> 2;
    const int lk = (l & 3) * 8;

    auto stage = [&](int buf, int kt) {
        #pragma unroll
        for (int q = 0; q < 2; ++q) {
            int ch = w * 2 + q;
            async16(&As[buf][ch * 512], A + (size_t)(m0 + ch * 16 + lrow) * lda + kt + lk);
        }
        #pragma unroll
        for (int q = 0; q < BQ; ++q) {
            int ch = w * BQ + q;
            async16(&Bs[buf][ch * 512], Bm + (size_t)(n0 + ch * 16 + lrow) * ldb + kt + lk);
        }
    };

    stage(0, 0);
    __syncthreads();
    const int nk = K >> 5;
    for (int ki = 0; ki < nk; ++ki) {
        const int cur = ki & 1;
        if (ki + 1 < nk) stage(cur ^ 1, (ki + 1) << 5);
        bf16x8 af[4], bfr[NI];
        #pragma unroll
        for (int mi = 0; mi < 4; mi++)
            af[mi] = *(const bf16x8*)&As[cur][(wr * 64 + mi * 16 + (l & 15)) * 32 + (l >> 4) * 8];
        #pragma unroll
        for (int ni = 0; ni < NI; ni++)
            bfr[ni] = *(const bf16x8*)&Bs[cur][(wc * (TN / 2) + ni * 16 + (l & 15)) * 32 + (l >> 4) * 8];
        #pragma unroll
        for (int mi = 0; mi < 4; mi++)
            #pragma unroll
            for (int ni = 0; ni < NI; ni++)
                acc[mi][ni] = __builtin_amdgcn_mfma_f32_16x16x32_bf16(af[mi], bfr[ni], acc[mi][ni], 0, 0, 0);
        __syncthreads();
    }
    #pragma unroll
    for (int mi = 0; mi < 4; mi++)
        #pragma unroll
        for (int ni = 0; ni < NI; ni++) {
            int row0 = m0 + wr * 64 + mi * 16 + (l >> 4) * 4;
            int col = n0 + wc * (TN / 2) + ni * 16 + (l & 15);
            f32x4 v = acc[mi][ni];
            #pragma unroll
            for (int r = 0; r < 4; r++) {
                int rr = row0 + r;
                float xv = v[r];
                if constexpr (KIND == 0 || KIND == 1) xv += bias[col];
                if constexpr (KIND == 1) xv += (float)addend[(size_t)rr * N + col];
                if constexpr (KIND == 2) {
                    if (col < Nreal) {
                        int t = rr >> 6, b = rr & 63;
                        // non-temporal: keep the 384MB logits stream out of the LLC
                        __builtin_nontemporal_store(
                            xv, &((float*)Cout)[((size_t)(b * TT + t)) * VV + col]);
                    }
                } else {
                    ((bf16*)Cout)[(size_t)rr * N + col] = (bf16)xv;
                }
            }
        }
    if constexpr (KIND == 2) {
        // per-row partial LSE over this wave's TN/2 cols (one partial / 128 cols)
        #pragma unroll
        for (int mi = 0; mi < 4; mi++) {
            #pragma unroll
            for (int r = 0; r < 4; r++) {
                float m = -1e30f, s = 0.f;
                #pragma unroll
                for (int ni = 0; ni < NI; ni++) {
                    int col = n0 + wc * (TN / 2) + ni * 16 + (l & 15);
                    if (col < Nreal) {
                        float v = acc[mi][ni][r];
                        float M = fmaxf(m, v);
                        s = s * __expf(m - M) + __expf(v - M);
                        m = M;
                    }
                }
                #pragma unroll
                for (int off = 1; off < 16; off <<= 1) {
                    float m2 = __shfl_xor(m, off);
                    float s2 = __shfl_xor(s, off);
                    float M = fmaxf(m, m2);
                    s = s * __expf(m - M) + s2 * __expf(m2 - M);
                    m = M;
                }
                if ((l & 15) == 0) {
                    int row = m0 + wr * 64 + mi * 16 + (l >> 4) * 4 + r;
                    size_t pidx = (size_t)row * PNB2 + ((n0 + wc * (TN / 2)) >> 7);
                    pm[pidx] = m; ps[pidx] = s;
                }
            }
        }
    }
}

// ---------------- persistent GRU recurrence (lo columns only) ----------------
// 64 blocks x 384 threads. Cross-block h via COMPACT hlo[T+1][64][1024] with
// relaxed sc0sc1 atomics (LLC = single coherence point; syncthreads drains
// vmcnt so stores are globally visible before the counter RMW). hfx copy via
// normal stores (read only after kernel end; end-of-kernel flush covers it).
__global__ __launch_bounds__(384, 1)
void k_rnn(const float* __restrict__ Whh,      // fp32 [6144][2048]
           const bf16* __restrict__ gi_b,      // [T*64][6144]
           const float* __restrict__ ghs,      // [64][6144]
           bf16* __restrict__ hlo,             // [T+1][64][1024] compact lo h
           bf16* __restrict__ hfx,             // [T+1][64][2048] full h (post-pass)
           uint32_t* __restrict__ ctr) {       // [TT]
    const int blk = blockIdx.x;          // 0..63 -> h cols [blk*16, +16)
    const int c0 = blk * 16;
    const int tid = threadIdx.x;
    const int wv = tid >> 6;             // 0..5
    const int l  = tid & 63;
    const int g  = wv >> 1;              // gate 0..2 (r,z,n)
    const int mh = wv & 1;               // M half (batches mh*32..+32)
    const int lc = l & 15, lk = l >> 4;
    __shared__ char h_lds[131072];       // h_t lo: [64][1024] bf16, XOR-swizzled
    __shared__ float ghl[3][64][17];

    // one-time: gate g's Whh rows (cols c0..c0+15, K=1024) -> registers as MFMA B-frags
    bf16x8 breg[32];
    {
        const float* wrow = Whh + ((size_t)(g * H2 + c0 + lc)) * H2;
        #pragma unroll
        for (int kt = 0; kt < 32; ++kt) {
            const float* p = wrow + kt * 32 + lk * 8;
            float4 v0 = *(const float4*)p;
            float4 v1 = *(const float4*)(p + 4);
            bf16x8 o;
            o[0] = (bf16)v0.x; o[1] = (bf16)v0.y; o[2] = (bf16)v0.z; o[3] = (bf16)v0.w;
            o[4] = (bf16)v1.x; o[5] = (bf16)v1.y; o[6] = (bf16)v1.z; o[7] = (bf16)v1.w;
            breg[kt] = o;
        }
    }
    // step-invariant ghs prefetch: epilogue waves wv<4, 4 elems/lane
    float pr[4], pz[4], pn[4];
    if (wv < 4) {
        #pragma unroll
        for (int r = 0; r < 4; ++r) {
            int b = wv * 16 + lk * 4 + r;
            size_t base = (size_t)b * G3 + c0 + lc;
            pr[r] = ghs[base];
            pz[r] = ghs[base + H2];
            pn[r] = ghs[base + 2 * H2];
        }
    }

    for (int t = 0; t < TT; ++t) {
        // ---- prefetch gi gate operands first (normal cached loads) ----
        bf16 qr[4], qz[4], qn[4];
        if (wv < 4) {
            const bf16* gp = gi_b + ((size_t)t * BB) * G3;
            #pragma unroll
            for (int r = 0; r < 4; ++r) {
                int b = wv * 16 + lk * 4 + r;
                size_t base = (size_t)b * G3 + c0 + lc;
                qr[r] = gp[base];
                qz[r] = gp[base + H2];
                qn[r] = gp[base + 2 * H2];
            }
        }

        // ---- stage h_t lo (compact, contiguous 128KB) into LDS ----
        {
            const uint64_t* hsrc = (const uint64_t*)(hlo + (size_t)t * BB * HH);
            #pragma unroll 1
            for (int i0 = 0; i0 < 44; i0 += 22) {
                uint64_t v[22];
                #pragma unroll
                for (int j = 0; j < 22; ++j) {
                    int idx = (i0 + j) * 384 + tid;        // uint64 index, 0..16383
                    if (idx < 16384)
                        v[j] = __hip_atomic_load(hsrc + idx, __ATOMIC_RELAXED,
                                                 __HIP_MEMORY_SCOPE_AGENT);
                }
                #pragma unroll
                for (int j = 0; j < 22; ++j) {
                    int idx = (i0 + j) * 384 + tid;
                    if (idx < 16384) {
                        int byte = idx * 8;
                        int swb = byte ^ (((byte >> 11) & 7) << 4);
                        *(uint64_t*)(h_lds + swb) = v[j];
                    }
                }
            }
        }
        __syncthreads();

        // ---- gh = h_t @ Wg^T for this wave's 16 cols, both M halves ----
        f32x4 acc0 = {}, acc1 = {};
        const int r0 = mh * 32 + lc, r1 = r0 + 16;
        const int sw = (lc & 7) << 4;
        #pragma unroll
        for (int kt = 0; kt < 32; ++kt) {
            int cbyte = kt * 64 + lk * 16;
            bf16x8 a0 = *(const bf16x8*)(h_lds + ((r0 * 2048 + cbyte) ^ sw));
            bf16x8 a1 = *(const bf16x8*)(h_lds + ((r1 * 2048 + cbyte) ^ sw));
            acc0 = __builtin_amdgcn_mfma_f32_16x16x32_bf16(a0, breg[kt], acc0, 0, 0, 0);
            acc1 = __builtin_amdgcn_mfma_f32_16x16x32_bf16(a1, breg[kt], acc1, 0, 0, 0);
        }
        #pragma unroll
        for (int r = 0; r < 4; ++r) {
            ghl[g][mh * 32 + lk * 4 + r][lc]      = acc0[r];
            ghl[g][mh * 32 + 16 + lk * 4 + r][lc] = acc1[r];
        }
        __syncthreads();

        // ---- epilogue on waves 0..3: batches wv*16..+16, col c0+lc ----
        if (wv < 4) {
            #pragma unroll
            for (int r = 0; r < 4; ++r) {
                int b = wv * 16 + lk * 4 + r;
                float hr = ghl[0][b][lc] + pr[r];
                float hz = ghl[1][b][lc] + pz[r];
                float hn = ghl[2][b][lc] + pn[r];
                float rg = sigmoidf_((float)qr[r] + hr);
                float zg = sigmoidf_((float)qz[r] + hz);
                float ng = tanhf((float)qn[r] + rg * hn);
                int hvb = (b * 2048 + (c0 + lc) * 2) ^ ((b & 7) << 4);
                float hv = (float)*(const bf16*)(h_lds + hvb);
                float hf = (1.f - zg) * ng + zg * hv;
                union { bf16 h; uint16_t u; } cv;
                cv.h = (bf16)hf;
                // recurrence-visible copy (LLC write-through)
                __hip_atomic_store(
                    (uint16_t*)&hlo[((size_t)(t + 1) * BB + b) * HH + c0 + lc],
                    cv.u, __ATOMIC_RELAXED, __HIP_MEMORY_SCOPE_AGENT);
                // post-pass copy (normal store, flushed at kernel end)
                hfx[((size_t)(t + 1) * BB + b) * H2 + c0 + lc] = cv.h;
            }
        }

        // ---- fence-free device barrier (R5 form; sound via sc0sc1 + vmcnt) ----
        if (t != TT - 1) {
            __syncthreads();   // drains vmcnt: hlo stores are LLC-visible
            if (tid == 0) {
                __hip_atomic_fetch_add(&ctr[t], 1u, __ATOMIC_RELAXED, __HIP_MEMORY_SCOPE_AGENT);
                while (__hip_atomic_load(&ctr[t], __ATOMIC_RELAXED, __HIP_MEMORY_SCOPE_AGENT) < RBLK)
                    __builtin_amdgcn_s_sleep(1);
            }
            __syncthreads();
        }
    }
}

// ---------------- deferred hi-column gates (parallel over t) ----------------
__global__ __launch_bounds__(256)
void k_hi(const bf16* __restrict__ hfx_,       // [T+1][64][2048] (reads slice t, lo cols)
          const float* __restrict__ ses_f,     // [64][1024]
          const bf16* __restrict__ Wrh,        // [3072][1024] reordered hi rows
          const bf16* __restrict__ gi_b,
          const float* __restrict__ ghs,
          bf16* __restrict__ hfx_out) {
    const int cblk = blockIdx.x;     // 0..15
    const int t    = blockIdx.y;     // 0..49
    const int tid = threadIdx.x;
    const int w = tid >> 6, l = tid & 63;
    __shared__ bf16 As[64 * 32];
    __shared__ bf16 Bs[192 * 32];
    f32x4 acc[12] = {};
    const int lrow = l >> 2;
    const int lk = (l & 3) * 8;
    const bf16* Abase = hfx_ + ((size_t)t * BB) * H2;
    for (int kt = 0; kt < HH; kt += 32) {
        async16(&As[w * 512], Abase + (size_t)(w * 16 + lrow) * H2 + kt + lk);
        #pragma unroll
        for (int q = 0; q < 3; ++q) {
            int cb = w * 3 + q;
            async16(&Bs[cb * 512], Wrh + (size_t)(cblk * 192 + cb * 16 + lrow) * HH + kt + lk);
        }
        __syncthreads();
        bf16x8 af = *(const bf16x8*)&As[(w * 16 + (l & 15)) * 32 + (l >> 4) * 8];
        #pragma unroll
        for (int j = 0; j < 12; j++) {
            bf16x8 bfj = *(const bf16x8*)&Bs[(j * 16 + (l & 15)) * 32 + (l >> 4) * 8];
            acc[j] = __builtin_amdgcn_mfma_f32_16x16x32_bf16(af, bfj, acc[j], 0, 0, 0);
        }
        __syncthreads();
    }
    #pragma unroll
    for (int jc = 0; jc < 4; jc++) {
        int ch = cblk * 64 + jc * 16 + (l & 15);      // hi col 0..1023
        #pragma unroll
        for (int r = 0; r < 4; r++) {
            int b = w * 16 + (l >> 4) * 4 + r;
            size_t gb = (size_t)(t * BB + b) * G3 + 1024 + ch;
            size_t sb = (size_t)b * G3 + 1024 + ch;
            float gr = (float)gi_b[gb];
            float gz = (float)gi_b[gb + H2];
            float gn = (float)gi_b[gb + 2 * H2];
            float hr = acc[jc][r]     + ghs[sb];
            float hz = acc[4 + jc][r] + ghs[sb + H2];
            float hn = acc[8 + jc][r] + ghs[sb + 2 * H2];
            float rg = sigmoidf_(gr + hr);
            float zg = sigmoidf_(gz + hz);
            float ng = tanhf(gn + rg * hn);
            float hv = ses_f[b * HH + ch];
            float hf = (1.f - zg) * ng + zg * hv;
            hfx_out[((size_t)(t + 1) * BB + b) * H2 + HH + ch] = (bf16)hf;
        }
    }
}

// ---------------- LSE reduce + ll ----------------
__global__ void k_lse(const float* __restrict__ pm, const float* __restrict__ ps,
                      const float* __restrict__ logits, const int* __restrict__ x,
                      float* __restrict__ ll, int pnb) {
    int row = blockIdx.x;          // t*64+b
    int t = row >> 6, b = row & 63;
    int l = threadIdx.x;           // 64
    float m = -1e30f, s = 0.f;
    for (int i = l; i < pnb; i += 64) {
        float mi = pm[(size_t)row * pnb + i];
        float si = ps[(size_t)row * pnb + i];
        float M = fmaxf(m, mi);
        s = s * __expf(m - M) + si * __expf(mi - M);
        m = M;
    }
    #pragma unroll
    for (int off = 32; off; off >>= 1) {
        float m2 = __shfl_down(m, off);
        float s2 = __shfl_down(s, off);
        float M = fmaxf(m, m2);
        s = s * __expf(m - M) + s2 * __expf(m2 - M);
        m = M;
    }
    if (l == 0) {
        float v = 0.f;
        if (t < TT - 1) {
            int nxt = x[b * TT + t + 1];
            v = logits[((size_t)(b * TT + t)) * VV + nxt] - (m + __logf(s));
        }
        ll[row] = v;
    }
}

__global__ void k_sumll(const float* __restrict__ ll_ws, float* __restrict__ out) {
    int b = threadIdx.x;
    if (b < BB) {
        float s = 0.f;
        for (int t = 0; t < TT; t++) s += ll_ws[t * BB + b];
        out[b] = s;
    }
}

// ---------------- host launcher ----------------
extern "C" void kernel_launch(void* const* d_in, const int* in_sizes, int n_in,
                              void* d_out, int out_size, void* d_ws, size_t ws_size,
                              hipStream_t stream) {
    const float* ses_encoding = (const float*)d_in[0];
    const int*   x            = (const int*)d_in[1];
    const float* emb_W        = (const float*)d_in[2];
    const float* gru_Wih      = (const float*)d_in[3];
    const float* gru_Whh      = (const float*)d_in[4];
    const float* gru_bih      = (const float*)d_in[5];
    const float* gru_bhh      = (const float*)d_in[6];
    const float* lin1_W       = (const float*)d_in[7];
    const float* lin1_b       = (const float*)d_in[8];
    const float* lin2_W       = (const float*)d_in[9];
    const float* lin2_b       = (const float*)d_in[10];
    const float* out_W        = (const float*)d_in[11];

    char* W = (char*)d_ws;
    size_t off = 0;
    auto take = [&](size_t bytes) { void* p = W + off; off += (bytes + 255) & ~(size_t)255; return p; };

    float* ses_f32 = (float*)take((size_t)BB * HH * 4);
    bf16* Wih_b    = (bf16*)take((size_t)G3 * EE * 2);
    bf16* Wrh_b    = (bf16*)take((size_t)3072 * HH * 2);
    bf16* lin2_b16 = (bf16*)take((size_t)EE * H2 * 2);
    bf16* outW_b   = (bf16*)take((size_t)NPAD2 * EE * 2);
    bf16* emb_b    = (bf16*)take((size_t)MM * EE * 2);
    bf16* gi_b     = (bf16*)take((size_t)MM * G3 * 2);
    float* ghs     = (float*)take((size_t)BB * G3 * 4);
    bf16* hlo      = (bf16*)take((size_t)(TT + 1) * BB * HH * 2);
    bf16* hfx      = (bf16*)take((size_t)(TT + 1) * BB * H2 * 2);
    bf16* hido_b   = (bf16*)take((size_t)MM * EE * 2);
    float* ll_ws   = (float*)take((size_t)MM * 4);
    float* pm      = (float*)take((size_t)MM * PNB2 * 4);
    float* ps      = (float*)take((size_t)MM * PNB2 * 4);
    uint32_t* ctr  = (uint32_t*)take((size_t)TT * 4);

    hipMemsetAsync(ctr, 0, (size_t)TT * 4, stream);

    // 1) weight conversions
    k_conv<<<(G3 * EE) / 1024, 256, 0, stream>>>(Wih_b, gru_Wih, G3 * EE);
    k_conv<<<(EE * H2) / 1024, 256, 0, stream>>>(lin2_b16, lin2_W, EE * H2);
    k_conv_outw<<<NPAD2, 256, 0, stream>>>(outW_b, out_W);
    k_conv_whhhi<<<3072, 256, 0, stream>>>(Wrh_b, gru_Whh);
    k_embed<<<MM, 256, 0, stream>>>(x, emb_W, emb_b);

    // 2) ses (fp32 + bf16 into hfx[0] lo and hlo[0]), ghs (fp32)
    sgemm64<0><<<HH / 64, 256, 0, stream>>>(ses_encoding, lin1_W, lin1_b, ses_f32,
                                            hfx, hlo, HH, SHH, SHH, SHH, 0, H2, HH);
    sgemm64<1><<<G3 / 64, 256, 0, stream>>>(ses_f32, gru_Whh, gru_bhh, ghs, nullptr,
                                            nullptr, G3, HH, HH, H2, HH, 0, 0);

    // 3) gi = emb @ Wih.T + bih (128x256 tile)
    gemm128<0, 256><<<dim3(G3 / 256, MM / 128), 256, 0, stream>>>(
        emb_b, Wih_b, gi_b, gru_bih, nullptr, nullptr, nullptr, G3, EE, EE, EE, 0);

    // 4) persistent recurrence (lo cols, weights-in-registers, compact hlo)
    k_rnn<<<RBLK, 384, 0, stream>>>(gru_Whh, gi_b, ghs, hlo, hfx, ctr);

    // 5) deferred hi-column half of h_full, all timesteps in parallel
    k_hi<<<dim3(16, TT), 256, 0, stream>>>(hfx, ses_f32, Wrh_b, gi_b, ghs, hfx);

    // 6) hid_o = h_full @ lin2_W.T + lin2_b + emb (128x128 tile)
    gemm128<1, 128><<<dim3(EE / 128, MM / 128), 256, 0, stream>>>(
        hfx + (size_t)BB * H2, lin2_b16, hido_b, lin2_b, emb_b, nullptr, nullptr,
        EE, H2, H2, H2, 0);

    // 7) logits -> d_out (NT stores), fused partial-LSE (128x256 tile)
    gemm128<2, 256><<<dim3(NPAD2 / 256, MM / 128), 256, 0, stream>>>(
        hido_b, outW_b, d_out, nullptr, nullptr, pm, ps, NPAD2, EE, EE, EE, VV);

    // 8) final LSE + log-likelihoods
    k_lse<<<MM, 64, 0, stream>>>(pm, ps, (const float*)d_out, x, ll_ws, PNB2);
    k_sumll<<<1, 64, 0, stream>>>(ll_ws, (float*)d_out + (size_t)BB * TT * VV);
}

// Round 14
// 1506.734 us; speedup vs baseline: 1.1460x; 1.1460x over previous
//
#include <hip/hip_runtime.h>
#include <hip/hip_bf16.h>
#include <stdint.h>

// Problem constants
#define VV   30000
#define EE   1024
#define SHH  2048
#define HH   1024
#define H2   2048
#define G3   6144      // 3*H2
#define BB   64
#define TT   50
#define PADT 10003
#define MM   3200      // T*B
#define NPAD 30080     // V padded to 128
#define RBLK 64        // persistent recurrence blocks
#define PNB  (NPAD / 64)   // 470 LSE partials per row

typedef __bf16 bf16;
typedef bf16  bf16x8 __attribute__((ext_vector_type(8)));
typedef bf16  bf16x4v __attribute__((ext_vector_type(4)));
typedef float f32x4 __attribute__((ext_vector_type(4)));

__device__ __forceinline__ void async16(void* lds_base, const void* gsrc) {
    __builtin_amdgcn_global_load_lds(
        (const __attribute__((address_space(1))) void*)gsrc,
        (__attribute__((address_space(3))) void*)lds_base, 16, 0, 0);
}

// bijective XCD-aware swizzle (m204)
__device__ __forceinline__ int xcd_swizzle(int lin, int nwg) {
    int q = nwg >> 3, r = nwg & 7;
    int x = lin & 7, o = lin >> 3;
    return (x < r ? x * (q + 1) : r * (q + 1) + (x - r) * q) + o;
}

__device__ __forceinline__ float sigmoidf_(float x) {
    return 1.f / (1.f + __expf(-x));
}

// ---------------- conversion kernels ----------------
__global__ __launch_bounds__(256) void k_conv(bf16* dst, const float* src, int n) {
    int i = (blockIdx.x * 256 + threadIdx.x) * 4;
    if (i + 3 >= n) return;
    float4 v = *(const float4*)&src[i];
    bf16x4v o; o[0] = (bf16)v.x; o[1] = (bf16)v.y; o[2] = (bf16)v.z; o[3] = (bf16)v.w;
    *(bf16x4v*)&dst[i] = o;
}

__global__ __launch_bounds__(256) void k_conv_outw(bf16* dst, const float* src) {
    int row = blockIdx.x;            // 0..30079
    int c = threadIdx.x * 4;
    bf16x4v o;
    if (row < VV) {
        float4 v = *(const float4*)&src[(size_t)row * EE + c];
        o[0] = (bf16)v.x; o[1] = (bf16)v.y; o[2] = (bf16)v.z; o[3] = (bf16)v.w;
    } else {
        o[0] = (bf16)0.f; o[1] = (bf16)0.f; o[2] = (bf16)0.f; o[3] = (bf16)0.f;
    }
    *(bf16x4v*)&dst[(size_t)row * EE + c] = o;
}

// Whh hi-col rows reordered for k_hi: dst row d = cblk*192 + g*64 + s
__global__ __launch_bounds__(256) void k_conv_whhhi(bf16* dst, const float* whh) {
    int d = blockIdx.x;              // 0..3071
    int cblk = d / 192, rem = d % 192, g = rem / 64, s = rem % 64;
    const float* srow = whh + (size_t)(g * H2 + 1024 + cblk * 64 + s) * H2;
    int c = threadIdx.x * 4;
    float4 v = *(const float4*)&srow[c];
    bf16x4v o; o[0] = (bf16)v.x; o[1] = (bf16)v.y; o[2] = (bf16)v.z; o[3] = (bf16)v.w;
    *(bf16x4v*)&dst[(size_t)d * HH + c] = o;
}

__global__ __launch_bounds__(256) void k_embed(const int* x, const float* embW, bf16* out) {
    int i = blockIdx.x;              // row = t*64+b
    int t = i >> 6, b = i & 63;
    int tok = x[b * TT + t];
    int e = threadIdx.x * 4;
    bf16x4v o;
    if (tok == PADT) {
        o[0] = (bf16)0.f; o[1] = (bf16)0.f; o[2] = (bf16)0.f; o[3] = (bf16)0.f;
    } else {
        float4 v = *(const float4*)&embW[(size_t)tok * EE + e];
        o[0] = (bf16)v.x; o[1] = (bf16)v.y; o[2] = (bf16)v.z; o[3] = (bf16)v.w;
    }
    *(bf16x4v*)&out[(size_t)i * EE + e] = o;
}

// ---------------- small fp32 GEMM (M=64): ses and ghs ----------------
// KIND 0: tanh, write fp32 (ld N) + bf16 (ldo) + bf16 (ldo2) ; KIND 1: fp32 out
template<int KIND>
__global__ __launch_bounds__(256)
void sgemm64(const float* __restrict__ A, const float* __restrict__ Bm,
             const float* __restrict__ bias, float* __restrict__ Of,
             bf16* __restrict__ Ob, bf16* __restrict__ Ob2,
             int N, int K, int lda, int ldb, int koff, int ldo, int ldo2) {
    int n0 = blockIdx.x * 64;
    int tid = threadIdx.x;
    int tr = tid >> 4, tc = tid & 15;
    __shared__ float As[64][33];
    __shared__ float Bs[64][33];
    float acc[4][4] = {};
    for (int k0 = 0; k0 < K; k0 += 32) {
        #pragma unroll
        for (int q = 0; q < 8; ++q) {
            int p = q * 256 + tid; int r = p >> 5, kk = p & 31;
            As[r][kk] = A[(size_t)r * lda + k0 + kk];
            Bs[r][kk] = Bm[(size_t)(n0 + r) * ldb + koff + k0 + kk];
        }
        __syncthreads();
        #pragma unroll
        for (int kk = 0; kk < 32; ++kk) {
            float a4[4], b4[4];
            #pragma unroll
            for (int i = 0; i < 4; i++) a4[i] = As[tr * 4 + i][kk];
            #pragma unroll
            for (int j = 0; j < 4; j++) b4[j] = Bs[tc * 4 + j][kk];
            #pragma unroll
            for (int i = 0; i < 4; i++)
                #pragma unroll
                for (int j = 0; j < 4; j++) acc[i][j] += a4[i] * b4[j];
        }
        __syncthreads();
    }
    #pragma unroll
    for (int i = 0; i < 4; i++)
        #pragma unroll
        for (int j = 0; j < 4; j++) {
            int row = tr * 4 + i, col = n0 + tc * 4 + j;
            float v = acc[i][j] + bias[col];
            if (KIND == 0) {
                v = tanhf(v);
                Of[(size_t)row * N + col] = v;
                Ob[(size_t)row * ldo + col] = (bf16)v;
                Ob2[(size_t)row * ldo2 + col] = (bf16)v;
            } else {
                Of[(size_t)row * N + col] = v;
            }
        }
}

// ---------------- big bf16 MFMA GEMM, 128x128 tile, 2-phase pipelined ----------------
// Block order: M-major (bx fastest) — A-panel reuse; NT writes sweep one
// M-band's columns (HBM row-buffer friendly). Double-buffered LDS: next
// K-tile's global_load_lds issued before current tile's MFMA; the single
// __syncthreads per iter drains vmcnt (prefetch) under the MFMA shadow.
// KIND 0: bf16 out + bias (gi) ; KIND 1: bf16 out + bias + bf16 addend (hid_o)
// KIND 2: f32 NT-store out, row-transposed, col guard, fused partial-LSE (logits)
template<int KIND>
__global__ __launch_bounds__(256)
void gemm128(const bf16* __restrict__ A, const bf16* __restrict__ Bm,
             void* __restrict__ Cout, const float* __restrict__ bias,
             const bf16* __restrict__ addend, float* __restrict__ pm,
             float* __restrict__ ps, int N, int K, int lda, int ldb, int Nreal) {
    int nwg = gridDim.x * gridDim.y;
    int lin = blockIdx.y * gridDim.x + blockIdx.x;
    int wg = xcd_swizzle(lin, nwg);
    int bx = wg % gridDim.x, by = wg / gridDim.x;
    const int n0 = bx * 128;
    const int m0 = by * 128;
    const int tid = threadIdx.x;
    const int w = tid >> 6, l = tid & 63;
    const int wr = w >> 1, wc = w & 1;
    __shared__ bf16 As[2][128 * 32];
    __shared__ bf16 Bs[2][128 * 32];
    f32x4 acc[4][4] = {};
    const int lrow = l >> 2;
    const int lk = (l & 3) * 8;

    auto stage = [&](int buf, int kt) {
        #pragma unroll
        for (int q = 0; q < 2; ++q) {
            int ch = w * 2 + q;
            async16(&As[buf][ch * 512], A + (size_t)(m0 + ch * 16 + lrow) * lda + kt + lk);
            async16(&Bs[buf][ch * 512], Bm + (size_t)(n0 + ch * 16 + lrow) * ldb + kt + lk);
        }
    };

    stage(0, 0);
    __syncthreads();                       // buf0 resident
    const int nk = K >> 5;
    for (int ki = 0; ki < nk; ++ki) {
        const int cur = ki & 1;
        if (ki + 1 < nk) stage(cur ^ 1, (ki + 1) << 5);   // prefetch next tile
        bf16x8 af[4], bfr[4];
        #pragma unroll
        for (int mi = 0; mi < 4; mi++)
            af[mi] = *(const bf16x8*)&As[cur][(wr * 64 + mi * 16 + (l & 15)) * 32 + (l >> 4) * 8];
        #pragma unroll
        for (int ni = 0; ni < 4; ni++)
            bfr[ni] = *(const bf16x8*)&Bs[cur][(wc * 64 + ni * 16 + (l & 15)) * 32 + (l >> 4) * 8];
        #pragma unroll
        for (int mi = 0; mi < 4; mi++)
            #pragma unroll
            for (int ni = 0; ni < 4; ni++)
                acc[mi][ni] = __builtin_amdgcn_mfma_f32_16x16x32_bf16(af[mi], bfr[ni], acc[mi][ni], 0, 0, 0);
        __syncthreads();                   // drains prefetch vmcnt + read/write sync
    }
    #pragma unroll
    for (int mi = 0; mi < 4; mi++)
        #pragma unroll
        for (int ni = 0; ni < 4; ni++) {
            int row0 = m0 + wr * 64 + mi * 16 + (l >> 4) * 4;
            int col = n0 + wc * 64 + ni * 16 + (l & 15);
            f32x4 v = acc[mi][ni];
            #pragma unroll
            for (int r = 0; r < 4; r++) {
                int rr = row0 + r;
                float xv = v[r];
                if constexpr (KIND == 0 || KIND == 1) xv += bias[col];
                if constexpr (KIND == 1) xv += (float)addend[(size_t)rr * N + col];
                if constexpr (KIND == 2) {
                    if (col < Nreal) {
                        int t = rr >> 6, b = rr & 63;
                        // non-temporal: keep the 384MB logits stream out of the LLC
                        __builtin_nontemporal_store(
                            xv, &((float*)Cout)[((size_t)(b * TT + t)) * VV + col]);
                    }
                } else {
                    ((bf16*)Cout)[(size_t)rr * N + col] = (bf16)xv;
                }
            }
        }
    if constexpr (KIND == 2) {
        #pragma unroll
        for (int mi = 0; mi < 4; mi++) {
            #pragma unroll
            for (int r = 0; r < 4; r++) {
                float m = -1e30f, s = 0.f;
                #pragma unroll
                for (int ni = 0; ni < 4; ni++) {
                    int col = n0 + wc * 64 + ni * 16 + (l & 15);
                    if (col < Nreal) {
                        float v = acc[mi][ni][r];
                        float M = fmaxf(m, v);
                        s = s * __expf(m - M) + __expf(v - M);
                        m = M;
                    }
                }
                #pragma unroll
                for (int off = 1; off < 16; off <<= 1) {
                    float m2 = __shfl_xor(m, off);
                    float s2 = __shfl_xor(s, off);
                    float M = fmaxf(m, m2);
                    s = s * __expf(m - M) + s2 * __expf(m2 - M);
                    m = M;
                }
                if ((l & 15) == 0) {
                    int row = m0 + wr * 64 + mi * 16 + (l >> 4) * 4 + r;
                    size_t pidx = (size_t)row * PNB + (n0 >> 6) + wc;
                    pm[pidx] = m; ps[pidx] = s;
                }
            }
        }
    }
}

// ---------------- persistent GRU recurrence (lo columns only) ----------------
// 64 blocks x 384 threads. Cross-block h via COMPACT hlo[T+1][64][1024] with
// relaxed sc0sc1 atomics (LLC = single coherence point; syncthreads drains
// vmcnt so stores are globally visible before the counter RMW). hfx copy via
// normal stores (read only after kernel end; end-of-kernel flush covers it).
__global__ __launch_bounds__(384, 1)
void k_rnn(const float* __restrict__ Whh,      // fp32 [6144][2048]
           const bf16* __restrict__ gi_b,      // [T*64][6144]
           const float* __restrict__ ghs,      // [64][6144]
           bf16* __restrict__ hlo,             // [T+1][64][1024] compact lo h
           bf16* __restrict__ hfx,             // [T+1][64][2048] full h (post-pass)
           uint32_t* __restrict__ ctr) {       // [TT]
    const int blk = blockIdx.x;          // 0..63 -> h cols [blk*16, +16)
    const int c0 = blk * 16;
    const int tid = threadIdx.x;
    const int wv = tid >> 6;             // 0..5
    const int l  = tid & 63;
    const int g  = wv >> 1;              // gate 0..2 (r,z,n)
    const int mh = wv & 1;               // M half (batches mh*32..+32)
    const int lc = l & 15, lk = l >> 4;
    __shared__ char h_lds[131072];       // h_t lo: [64][1024] bf16, XOR-swizzled
    __shared__ float ghl[3][64][17];

    // one-time: gate g's Whh rows (cols c0..c0+15, K=1024) -> registers as MFMA B-frags
    bf16x8 breg[32];
    {
        const float* wrow = Whh + ((size_t)(g * H2 + c0 + lc)) * H2;
        #pragma unroll
        for (int kt = 0; kt < 32; ++kt) {
            const float* p = wrow + kt * 32 + lk * 8;
            float4 v0 = *(const float4*)p;
            float4 v1 = *(const float4*)(p + 4);
            bf16x8 o;
            o[0] = (bf16)v0.x; o[1] = (bf16)v0.y; o[2] = (bf16)v0.z; o[3] = (bf16)v0.w;
            o[4] = (bf16)v1.x; o[5] = (bf16)v1.y; o[6] = (bf16)v1.z; o[7] = (bf16)v1.w;
            breg[kt] = o;
        }
    }
    // step-invariant ghs prefetch: epilogue waves wv<4, 4 elems/lane
    float pr[4], pz[4], pn[4];
    if (wv < 4) {
        #pragma unroll
        for (int r = 0; r < 4; ++r) {
            int b = wv * 16 + lk * 4 + r;
            size_t base = (size_t)b * G3 + c0 + lc;
            pr[r] = ghs[base];
            pz[r] = ghs[base + H2];
            pn[r] = ghs[base + 2 * H2];
        }
    }

    for (int t = 0; t < TT; ++t) {
        // ---- prefetch gi gate operands first (normal cached loads) ----
        bf16 qr[4], qz[4], qn[4];
        if (wv < 4) {
            const bf16* gp = gi_b + ((size_t)t * BB) * G3;
            #pragma unroll
            for (int r = 0; r < 4; ++r) {
                int b = wv * 16 + lk * 4 + r;
                size_t base = (size_t)b * G3 + c0 + lc;
                qr[r] = gp[base];
                qz[r] = gp[base + H2];
                qn[r] = gp[base + 2 * H2];
            }
        }

        // ---- stage h_t lo (compact, contiguous 128KB) into LDS ----
        {
            const uint64_t* hsrc = (const uint64_t*)(hlo + (size_t)t * BB * HH);
            #pragma unroll 1
            for (int i0 = 0; i0 < 44; i0 += 22) {
                uint64_t v[22];
                #pragma unroll
                for (int j = 0; j < 22; ++j) {
                    int idx = (i0 + j) * 384 + tid;        // uint64 index, 0..16383
                    if (idx < 16384)
                        v[j] = __hip_atomic_load(hsrc + idx, __ATOMIC_RELAXED,
                                                 __HIP_MEMORY_SCOPE_AGENT);
                }
                #pragma unroll
                for (int j = 0; j < 22; ++j) {
                    int idx = (i0 + j) * 384 + tid;
                    if (idx < 16384) {
                        int byte = idx * 8;
                        int swb = byte ^ (((byte >> 11) & 7) << 4);
                        *(uint64_t*)(h_lds + swb) = v[j];
                    }
                }
            }
        }
        __syncthreads();

        // ---- gh = h_t @ Wg^T for this wave's 16 cols, both M halves ----
        f32x4 acc0 = {}, acc1 = {};
        const int r0 = mh * 32 + lc, r1 = r0 + 16;
        const int sw = (lc & 7) << 4;
        #pragma unroll
        for (int kt = 0; kt < 32; ++kt) {
            int cbyte = kt * 64 + lk * 16;
            bf16x8 a0 = *(const bf16x8*)(h_lds + ((r0 * 2048 + cbyte) ^ sw));
            bf16x8 a1 = *(const bf16x8*)(h_lds + ((r1 * 2048 + cbyte) ^ sw));
            acc0 = __builtin_amdgcn_mfma_f32_16x16x32_bf16(a0, breg[kt], acc0, 0, 0, 0);
            acc1 = __builtin_amdgcn_mfma_f32_16x16x32_bf16(a1, breg[kt], acc1, 0, 0, 0);
        }
        #pragma unroll
        for (int r = 0; r < 4; ++r) {
            ghl[g][mh * 32 + lk * 4 + r][lc]      = acc0[r];
            ghl[g][mh * 32 + 16 + lk * 4 + r][lc] = acc1[r];
        }
        __syncthreads();

        // ---- epilogue on waves 0..3: batches wv*16..+16, col c0+lc ----
        if (wv < 4) {
            #pragma unroll
            for (int r = 0; r < 4; ++r) {
                int b = wv * 16 + lk * 4 + r;
                float hr = ghl[0][b][lc] + pr[r];
                float hz = ghl[1][b][lc] + pz[r];
                float hn = ghl[2][b][lc] + pn[r];
                float rg = sigmoidf_((float)qr[r] + hr);
                float zg = sigmoidf_((float)qz[r] + hz);
                float ng = tanhf((float)qn[r] + rg * hn);
                int hvb = (b * 2048 + (c0 + lc) * 2) ^ ((b & 7) << 4);
                float hv = (float)*(const bf16*)(h_lds + hvb);
                float hf = (1.f - zg) * ng + zg * hv;
                union { bf16 h; uint16_t u; } cv;
                cv.h = (bf16)hf;
                // recurrence-visible copy (LLC write-through)
                __hip_atomic_store(
                    (uint16_t*)&hlo[((size_t)(t + 1) * BB + b) * HH + c0 + lc],
                    cv.u, __ATOMIC_RELAXED, __HIP_MEMORY_SCOPE_AGENT);
                // post-pass copy (normal store, flushed at kernel end)
                hfx[((size_t)(t + 1) * BB + b) * H2 + c0 + lc] = cv.h;
            }
        }

        // ---- fence-free device barrier (R5 form; sound via sc0sc1 + vmcnt) ----
        if (t != TT - 1) {
            __syncthreads();   // drains vmcnt: hlo stores are LLC-visible
            if (tid == 0) {
                __hip_atomic_fetch_add(&ctr[t], 1u, __ATOMIC_RELAXED, __HIP_MEMORY_SCOPE_AGENT);
                while (__hip_atomic_load(&ctr[t], __ATOMIC_RELAXED, __HIP_MEMORY_SCOPE_AGENT) < RBLK)
                    __builtin_amdgcn_s_sleep(1);
            }
            __syncthreads();
        }
    }
}

// ---------------- deferred hi-column gates (parallel over t) ----------------
__global__ __launch_bounds__(256)
void k_hi(const bf16* __restrict__ hfx_,       // [T+1][64][2048] (reads slice t, lo cols)
          const float* __restrict__ ses_f,     // [64][1024]
          const bf16* __restrict__ Wrh,        // [3072][1024] reordered hi rows
          const bf16* __restrict__ gi_b,
          const float* __restrict__ ghs,
          bf16* __restrict__ hfx_out) {
    const int cblk = blockIdx.x;     // 0..15
    const int t    = blockIdx.y;     // 0..49
    const int tid = threadIdx.x;
    const int w = tid >> 6, l = tid & 63;
    __shared__ bf16 As[64 * 32];
    __shared__ bf16 Bs[192 * 32];
    f32x4 acc[12] = {};
    const int lrow = l >> 2;
    const int lk = (l & 3) * 8;
    const bf16* Abase = hfx_ + ((size_t)t * BB) * H2;
    for (int kt = 0; kt < HH; kt += 32) {
        async16(&As[w * 512], Abase + (size_t)(w * 16 + lrow) * H2 + kt + lk);
        #pragma unroll
        for (int q = 0; q < 3; ++q) {
            int cb = w * 3 + q;
            async16(&Bs[cb * 512], Wrh + (size_t)(cblk * 192 + cb * 16 + lrow) * HH + kt + lk);
        }
        __syncthreads();
        bf16x8 af = *(const bf16x8*)&As[(w * 16 + (l & 15)) * 32 + (l >> 4) * 8];
        #pragma unroll
        for (int j = 0; j < 12; j++) {
            bf16x8 bfj = *(const bf16x8*)&Bs[(j * 16 + (l & 15)) * 32 + (l >> 4) * 8];
            acc[j] = __builtin_amdgcn_mfma_f32_16x16x32_bf16(af, bfj, acc[j], 0, 0, 0);
        }
        __syncthreads();
    }
    #pragma unroll
    for (int jc = 0; jc < 4; jc++) {
        int ch = cblk * 64 + jc * 16 + (l & 15);      // hi col 0..1023
        #pragma unroll
        for (int r = 0; r < 4; r++) {
            int b = w * 16 + (l >> 4) * 4 + r;
            size_t gb = (size_t)(t * BB + b) * G3 + 1024 + ch;
            size_t sb = (size_t)b * G3 + 1024 + ch;
            float gr = (float)gi_b[gb];
            float gz = (float)gi_b[gb + H2];
            float gn = (float)gi_b[gb + 2 * H2];
            float hr = acc[jc][r]     + ghs[sb];
            float hz = acc[4 + jc][r] + ghs[sb + H2];
            float hn = acc[8 + jc][r] + ghs[sb + 2 * H2];
            float rg = sigmoidf_(gr + hr);
            float zg = sigmoidf_(gz + hz);
            float ng = tanhf(gn + rg * hn);
            float hv = ses_f[b * HH + ch];
            float hf = (1.f - zg) * ng + zg * hv;
            hfx_out[((size_t)(t + 1) * BB + b) * H2 + HH + ch] = (bf16)hf;
        }
    }
}

// ---------------- LSE reduce + ll ----------------
__global__ void k_lse(const float* __restrict__ pm, const float* __restrict__ ps,
                      const float* __restrict__ logits, const int* __restrict__ x,
                      float* __restrict__ ll) {
    int row = blockIdx.x;          // t*64+b
    int t = row >> 6, b = row & 63;
    int l = threadIdx.x;           // 64
    float m = -1e30f, s = 0.f;
    for (int i = l; i < PNB; i += 64) {
        float mi = pm[(size_t)row * PNB + i];
        float si = ps[(size_t)row * PNB + i];
        float M = fmaxf(m, mi);
        s = s * __expf(m - M) + si * __expf(mi - M);
        m = M;
    }
    #pragma unroll
    for (int off = 32; off; off >>= 1) {
        float m2 = __shfl_down(m, off);
        float s2 = __shfl_down(s, off);
        float M = fmaxf(m, m2);
        s = s * __expf(m - M) + s2 * __expf(m2 - M);
        m = M;
    }
    if (l == 0) {
        float v = 0.f;
        if (t < TT - 1) {
            int nxt = x[b * TT + t + 1];
            v = logits[((size_t)(b * TT + t)) * VV + nxt] - (m + __logf(s));
        }
        ll[row] = v;
    }
}

__global__ void k_sumll(const float* __restrict__ ll_ws, float* __restrict__ out) {
    int b = threadIdx.x;
    if (b < BB) {
        float s = 0.f;
        for (int t = 0; t < TT; t++) s += ll_ws[t * BB + b];
        out[b] = s;
    }
}

// ---------------- host launcher ----------------
extern "C" void kernel_launch(void* const* d_in, const int* in_sizes, int n_in,
                              void* d_out, int out_size, void* d_ws, size_t ws_size,
                              hipStream_t stream) {
    const float* ses_encoding = (const float*)d_in[0];
    const int*   x            = (const int*)d_in[1];
    const float* emb_W        = (const float*)d_in[2];
    const float* gru_Wih      = (const float*)d_in[3];
    const float* gru_Whh      = (const float*)d_in[4];
    const float* gru_bih      = (const float*)d_in[5];
    const float* gru_bhh      = (const float*)d_in[6];
    const float* lin1_W       = (const float*)d_in[7];
    const float* lin1_b       = (const float*)d_in[8];
    const float* lin2_W       = (const float*)d_in[9];
    const float* lin2_b       = (const float*)d_in[10];
    const float* out_W        = (const float*)d_in[11];

    char* W = (char*)d_ws;
    size_t off = 0;
    auto take = [&](size_t bytes) { void* p = W + off; off += (bytes + 255) & ~(size_t)255; return p; };

    float* ses_f32 = (float*)take((size_t)BB * HH * 4);
    bf16* Wih_b    = (bf16*)take((size_t)G3 * EE * 2);
    bf16* Wrh_b    = (bf16*)take((size_t)3072 * HH * 2);
    bf16* lin2_b16 = (bf16*)take((size_t)EE * H2 * 2);
    bf16* outW_b   = (bf16*)take((size_t)NPAD * EE * 2);
    bf16* emb_b    = (bf16*)take((size_t)MM * EE * 2);
    bf16* gi_b     = (bf16*)take((size_t)MM * G3 * 2);
    float* ghs     = (float*)take((size_t)BB * G3 * 4);
    bf16* hlo      = (bf16*)take((size_t)(TT + 1) * BB * HH * 2);
    bf16* hfx      = (bf16*)take((size_t)(TT + 1) * BB * H2 * 2);
    bf16* hido_b   = (bf16*)take((size_t)MM * EE * 2);
    float* ll_ws   = (float*)take((size_t)MM * 4);
    float* pm      = (float*)take((size_t)MM * PNB * 4);
    float* ps      = (float*)take((size_t)MM * PNB * 4);
    uint32_t* ctr  = (uint32_t*)take((size_t)TT * 4);

    hipMemsetAsync(ctr, 0, (size_t)TT * 4, stream);

    // 1) weight conversions
    k_conv<<<(G3 * EE) / 1024, 256, 0, stream>>>(Wih_b, gru_Wih, G3 * EE);
    k_conv<<<(EE * H2) / 1024, 256, 0, stream>>>(lin2_b16, lin2_W, EE * H2);
    k_conv_outw<<<NPAD, 256, 0, stream>>>(outW_b, out_W);
    k_conv_whhhi<<<3072, 256, 0, stream>>>(Wrh_b, gru_Whh);
    k_embed<<<MM, 256, 0, stream>>>(x, emb_W, emb_b);

    // 2) ses (fp32 + bf16 into hfx[0] lo and hlo[0]), ghs (fp32)
    sgemm64<0><<<HH / 64, 256, 0, stream>>>(ses_encoding, lin1_W, lin1_b, ses_f32,
                                            hfx, hlo, HH, SHH, SHH, SHH, 0, H2, HH);
    sgemm64<1><<<G3 / 64, 256, 0, stream>>>(ses_f32, gru_Whh, gru_bhh, ghs, nullptr,
                                            nullptr, G3, HH, HH, H2, HH, 0, 0);

    // 3) gi = emb @ Wih.T + bih
    gemm128<0><<<dim3(G3 / 128, MM / 128), 256, 0, stream>>>(
        emb_b, Wih_b, gi_b, gru_bih, nullptr, nullptr, nullptr, G3, EE, EE, EE, 0);

    // 4) persistent recurrence (lo cols, weights-in-registers, compact hlo)
    k_rnn<<<RBLK, 384, 0, stream>>>(gru_Whh, gi_b, ghs, hlo, hfx, ctr);

    // 5) deferred hi-column half of h_full, all timesteps in parallel
    k_hi<<<dim3(16, TT), 256, 0, stream>>>(hfx, ses_f32, Wrh_b, gi_b, ghs, hfx);

    // 6) hid_o = h_full @ lin2_W.T + lin2_b + emb
    gemm128<1><<<dim3(EE / 128, MM / 128), 256, 0, stream>>>(
        hfx + (size_t)BB * H2, lin2_b16, hido_b, lin2_b, emb_b, nullptr, nullptr,
        EE, H2, H2, H2, 0);

    // 7) logits -> d_out (NT stores), fused partial-LSE
    gemm128<2><<<dim3(NPAD / 128, MM / 128), 256, 0, stream>>>(
        hido_b, outW_b, d_out, nullptr, nullptr, pm, ps, NPAD, EE, EE, EE, VV);

    // 8) final LSE + log-likelihoods
    k_lse<<<MM, 64, 0, stream>>>(pm, ps, (const float*)d_out, x, ll_ws);
    k_sumll<<<1, 64, 0, stream>>>(ll_ws, (float*)d_out + (size_t)BB * TT * VV);
}